// Round 22
// baseline (8815.682 us; speedup 1.0000x reference)
//
#include <hip/hip_runtime.h>

typedef _Float16 half_t;
typedef _Float16 half8 __attribute__((ext_vector_type(8)));
typedef float floatx4 __attribute__((ext_vector_type(4)));
typedef int int4v __attribute__((ext_vector_type(4)));
typedef unsigned uint4v __attribute__((ext_vector_type(4)));
typedef unsigned char uchar;

#define NSTEP 512
#define INV2048 (1.0f / 2048.0f)
#define NSLOT 64
#define SLOTE 65536  // 64 batch x 1024 units per ring slot (f16)
#define FSTRIDE 64   // flag counters 256B apart (one line each)

// ---- e5m2 codec: encode = f16 top byte (w/ rounding); decode = byte<<8 ----
__device__ __forceinline__ uchar enc_e5m2(float x) {
  half_t h = (half_t)x;
  unsigned b = (unsigned)__builtin_bit_cast(unsigned short, h);
  return (uchar)(((b + 0x80u) >> 8) & 0xffu);
}

__device__ __forceinline__ half8 dec8(unsigned w0, unsigned w1) {
  uint4v u;
  u[0] = ((w0 & 0x000000ffu) << 8) | ((w0 & 0x0000ff00u) << 16);
  u[1] = ((w0 & 0x00ff0000u) >> 8) | (w0 & 0xff000000u);
  u[2] = ((w1 & 0x000000ffu) << 8) | ((w1 & 0x0000ff00u) << 16);
  u[3] = ((w1 & 0x00ff0000u) >> 8) | (w1 & 0xff000000u);
  return __builtin_bit_cast(half8, u);
}

// hi blob: [layer(2)][wg(128)][wv(8)][frag(16)][lane(64)][i(8)] f16 (32 MB)
// lo blob: same index space, e5m2 of (v-hi)*2048 (16 MB)
// frag = prt*8 + kk*2 + mt (prt: 0=x-K-space, 1=h-K-space).
// A-row mloc = mt*16+(lane&15) -> gate=mloc>>3, u=mloc&7; grow = gate*1024+wg*8+u.
// k = prt*1024 + wv*128 + kk*32 + (lane>>4)*8 + i;  k<1024 Wih else Whh.
__global__ void conv_w(const float* __restrict__ Wih, const float* __restrict__ Whh,
                       half_t* __restrict__ whi, uchar* __restrict__ wlo) {
  long e = (long)blockIdx.x * 256 + threadIdx.x;  // 2^24
  int i    = (int)(e & 7);
  int lane = (int)((e >> 3) & 63);
  int frag = (int)((e >> 9) & 15);
  int wv   = (int)((e >> 13) & 7);
  int wg   = (int)((e >> 16) & 127);
  int layer = (int)((e >> 23) & 1);
  int mt = frag & 1, kk = (frag >> 1) & 3, prt = frag >> 3;
  int mloc = mt * 16 + (lane & 15);
  int grow = (mloc >> 3) * 1024 + wg * 8 + (mloc & 7);
  int k = prt * 1024 + wv * 128 + kk * 32 + ((lane >> 4) * 8) + i;
  long base = ((long)layer << 22) + (long)grow * 1024;
  float v = (k < 1024) ? Wih[base + k] : Whh[base + (k - 1024)];
  half_t hi = (half_t)v;
  whi[e] = hi;
  wlo[e] = enc_e5m2((v - (float)hi) * 2048.0f);
}

__device__ __forceinline__ float sigm(float x) { return 1.f / (1.f + __expf(-x)); }
__device__ __forceinline__ float tanh_f(float x) {
  x = fminf(15.f, fmaxf(-15.f, x));
  float e = __expf(-2.f * x);
  return (1.f - e) / (1.f + e);
}

// narrow poll: wave waits until 16 consecutive per-WG counters (strided) >= n
__device__ __forceinline__ void pollN(const int* fbase, int first, int n, int lane) {
  const int* p = fbase + (first + (lane & 15)) * FSTRIDE;
  while (__hip_atomic_load(p, __ATOMIC_RELAXED, __HIP_MEMORY_SCOPE_AGENT) < n)
    __builtin_amdgcn_s_sleep(2);
}

// full poll: all 128 counters >= n (amortized ring guard)
__device__ __forceinline__ void pollFull(const int* fbase, int n, int lane) {
  const int* p0 = fbase + lane * FSTRIDE;
  const int* p1 = fbase + (64 + lane) * FSTRIDE;
  for (;;) {
    int v0 = __hip_atomic_load(p0, __ATOMIC_RELAXED, __HIP_MEMORY_SCOPE_AGENT);
    int v1 = __hip_atomic_load(p1, __ATOMIC_RELAXED, __HIP_MEMORY_SCOPE_AGENT);
    if (__all((v0 >= n) && (v1 >= n))) break;
    __builtin_amdgcn_s_sleep(2);
  }
}

// 256 WGs x 512 thr. WGs [0,128): layer 0; [128,256): layer 1. Decoupled layers,
// narrow single-hop flags (R21). NEW: (a) L0 prefetches next step's emb rows into
// its XCD L2 right after its flag store -> the random-HBM gather tail leaves the
// critical chain; (b) L0 computes x BEFORE its recurrence poll; (c) L1 splits its
// two polls so x-work overlaps the recurrence wait. One barrier/step, part
// double-buffered; hi-weights in 64 VGPRs, e5m2 lo in 32; h rings 64 slots f16;
// acquire-fence every 32 own-steps (ring reuse 64).
__launch_bounds__(512, 1)
__global__ void lstm_main(const int* __restrict__ tokens, const float* __restrict__ emb,
                          const float* __restrict__ bih, const float* __restrict__ bhh,
                          const half_t* __restrict__ whi, const uchar* __restrict__ wlo,
                          half_t* __restrict__ h1h, half_t* __restrict__ h2h,
                          int* __restrict__ fc, float* __restrict__ out) {
  __shared__ float part[2][8][32][68];   // 139 KB, double-buffered per-wave slices
  __shared__ int dcnt;                   // monotonic completion counter
  const int wgid = blockIdx.x;
  const int layer = wgid >> 7;
  const int wg = wgid & 127;
  const int tid = (int)threadIdx.x;
  const int wv = tid >> 6;
  const int lane = tid & 63;
  const int ln15 = lane & 15;
  const int kr = (lane >> 4) * 8;

  const int* f0 = fc;                  // layer-0 counters, FSTRIDE apart
  const int* f1 = fc + 128 * FSTRIDE;  // layer-1 counters

  // hi-weights -> 64 persistent VGPRs (frag 0..7 = x, 8..15 = h)
  half8 whi_r[16];
  {
    const half_t* wb = whi + (((long)(layer * 128 + wg)) << 16) + wv * 8192;
    #pragma unroll
    for (int f = 0; f < 16; ++f)
      whi_r[f] = *(const half8*)(wb + f * 512 + lane * 8);
  }
  // e5m2 lo-weights -> 32 persistent VGPRs
  unsigned lw[16][2];
  {
    const uchar* lobw = wlo + (((long)(layer * 128 + wg)) << 16) + wv * 8192;
    #pragma unroll
    for (int f = 0; f < 16; ++f) {
      const unsigned* l = (const unsigned*)(lobw + (f << 9) + lane * 8);
      lw[f][0] = l[0]; lw[f][1] = l[1];
    }
  }

  float bsum[4];
  {
    int u = tid & 7;
    for (int g = 0; g < 4; ++g) {
      int bi = layer * 4096 + g * 1024 + wg * 8 + u;
      bsum[g] = bih[bi] + bhh[bi];
    }
  }
  float c = 0.f;
  if (tid == 0) dcnt = 0;
  __syncthreads();

  // prologue prefetch of emb rows for t=0 (L0)
  if (layer == 0) {
    float dummy = 0.f;
    #pragma unroll
    for (int nt = 0; nt < 4; ++nt) {
      int tk2 = tokens[nt * 16 + ln15];
      const float* r = emb + (long)tk2 * 1024 + wv * 128;
      #pragma unroll
      for (int j = 0; j < 4; ++j) dummy += r[j * 32];
    }
    asm volatile("" :: "v"(dummy));
  }

  for (int t = 0; t < NSTEP; ++t) {
    floatx4 zero = {0.f, 0.f, 0.f, 0.f};
    floatx4 acc_h[2][4], acc_l[2][4];
    for (int a = 0; a < 2; ++a)
      for (int b = 0; b < 4; ++b) { acc_h[a][b] = zero; acc_l[a][b] = zero; }

    if (layer == 0) {
      // ring-overwrite guard (amortized, margin 32)
      if ((t & 15) == 0 && t >= 33) pollFull(f1, t - 32, lane);

      // ---- x-part FIRST (no flag dependency; emb rows L2-warm from prefetch) ----
      int tk[4]; const float* rowp[4]; float msk[4];
      #pragma unroll
      for (int nt = 0; nt < 4; ++nt) {
        tk[nt] = tokens[t * 64 + nt * 16 + ln15];
        rowp[nt] = emb + (long)tk[nt] * 1024;
        msk[nt] = (tk[nt] == 0) ? 0.f : 1.f;
      }
      floatx4 bx0[2][4], bx1[2][4];
      {
        int kb = wv * 128 + kr;
        #pragma unroll
        for (int nt = 0; nt < 4; ++nt) {
          bx0[0][nt] = *(const floatx4*)(rowp[nt] + kb);
          bx1[0][nt] = *(const floatx4*)(rowp[nt] + kb + 4);
        }
      }
      #pragma unroll
      for (int kk = 0; kk < 4; ++kk) {
        const int cb = kk & 1, nx = cb ^ 1;
        if (kk < 3) {
          int kb = wv * 128 + (kk + 1) * 32 + kr;
          #pragma unroll
          for (int nt = 0; nt < 4; ++nt) {
            bx0[nx][nt] = *(const floatx4*)(rowp[nt] + kb);
            bx1[nx][nt] = *(const floatx4*)(rowp[nt] + kb + 4);
          }
        }
        half8 ah0 = whi_r[kk * 2];
        half8 ah1 = whi_r[kk * 2 + 1];
        half8 al0 = dec8(lw[kk * 2][0], lw[kk * 2][1]);
        half8 al1 = dec8(lw[kk * 2 + 1][0], lw[kk * 2 + 1][1]);
        #pragma unroll
        for (int nt = 0; nt < 4; ++nt) {
          half8 bh;
          #pragma unroll
          for (int q = 0; q < 4; ++q) {
            bh[q]     = (half_t)(bx0[cb][nt][q] * msk[nt]);
            bh[q + 4] = (half_t)(bx1[cb][nt][q] * msk[nt]);
          }
          acc_h[0][nt] = __builtin_amdgcn_mfma_f32_16x16x32_f16(ah0, bh, acc_h[0][nt], 0, 0, 0);
          acc_h[1][nt] = __builtin_amdgcn_mfma_f32_16x16x32_f16(ah1, bh, acc_h[1][nt], 0, 0, 0);
          acc_l[0][nt] = __builtin_amdgcn_mfma_f32_16x16x32_f16(al0, bh, acc_l[0][nt], 0, 0, 0);
          acc_l[1][nt] = __builtin_amdgcn_mfma_f32_16x16x32_f16(al1, bh, acc_l[1][nt], 0, 0, 0);
        }
      }
      // ---- recurrence poll AFTER x ----
      if (t > 0) pollN(f0, wv * 16, t, lane);
    } else {
      // ---- L1: poll x-dep, compute x, THEN poll recurrence (split) ----
      pollN(f0, wv * 16, t + 1, lane);   // h1[t] ready for this slice
      const half_t* abh = h1h + (long)(t & (NSLOT - 1)) * SLOTE;
      const int kofs = wv * 128;
      half8 bufh[4][4];
      #pragma unroll
      for (int kk = 0; kk < 4; ++kk) {
        int kb = kofs + kk * 32 + kr;
        #pragma unroll
        for (int nt = 0; nt < 4; ++nt)
          bufh[kk][nt] = *(const half8*)(abh + (nt * 16 + ln15) * 1024 + kb);
      }
      #pragma unroll
      for (int kk = 0; kk < 4; ++kk) {
        half8 ah0 = whi_r[kk * 2];
        half8 ah1 = whi_r[kk * 2 + 1];
        half8 al0 = dec8(lw[kk * 2][0], lw[kk * 2][1]);
        half8 al1 = dec8(lw[kk * 2 + 1][0], lw[kk * 2 + 1][1]);
        #pragma unroll
        for (int nt = 0; nt < 4; ++nt) {
          half8 bh = bufh[kk][nt];
          acc_h[0][nt] = __builtin_amdgcn_mfma_f32_16x16x32_f16(ah0, bh, acc_h[0][nt], 0, 0, 0);
          acc_h[1][nt] = __builtin_amdgcn_mfma_f32_16x16x32_f16(ah1, bh, acc_h[1][nt], 0, 0, 0);
          acc_l[0][nt] = __builtin_amdgcn_mfma_f32_16x16x32_f16(al0, bh, acc_l[0][nt], 0, 0, 0);
          acc_l[1][nt] = __builtin_amdgcn_mfma_f32_16x16x32_f16(al1, bh, acc_l[1][nt], 0, 0, 0);
        }
      }
      if (t > 0) pollN(f1, wv * 16, t, lane);  // own h2[t-1] for this slice
    }

    // ---- h-part: 128 k per wave (4 kk), frags 8..15 ----
    if (t > 0) {
      const half_t* abh = (layer == 0 ? h1h : h2h) + (long)((t - 1) & (NSLOT - 1)) * SLOTE;
      const int kofs = wv * 128;
      half8 bufh[4][4];
      #pragma unroll
      for (int kk = 0; kk < 4; ++kk) {
        int kb = kofs + kk * 32 + kr;
        #pragma unroll
        for (int nt = 0; nt < 4; ++nt)
          bufh[kk][nt] = *(const half8*)(abh + (nt * 16 + ln15) * 1024 + kb);
      }
      #pragma unroll
      for (int kk = 0; kk < 4; ++kk) {
        half8 ah0 = whi_r[8 + kk * 2];
        half8 ah1 = whi_r[8 + kk * 2 + 1];
        half8 al0 = dec8(lw[8 + kk * 2][0], lw[8 + kk * 2][1]);
        half8 al1 = dec8(lw[8 + kk * 2 + 1][0], lw[8 + kk * 2 + 1][1]);
        #pragma unroll
        for (int nt = 0; nt < 4; ++nt) {
          half8 bh = bufh[kk][nt];
          acc_h[0][nt] = __builtin_amdgcn_mfma_f32_16x16x32_f16(ah0, bh, acc_h[0][nt], 0, 0, 0);
          acc_h[1][nt] = __builtin_amdgcn_mfma_f32_16x16x32_f16(ah1, bh, acc_h[1][nt], 0, 0, 0);
          acc_l[0][nt] = __builtin_amdgcn_mfma_f32_16x16x32_f16(al0, bh, acc_l[0][nt], 0, 0, 0);
          acc_l[1][nt] = __builtin_amdgcn_mfma_f32_16x16x32_f16(al1, bh, acc_l[1][nt], 0, 0, 0);
        }
      }
    }

    // plain per-wave slice write into buffer t&1 (exact coverage)
    const int pb = t & 1;
    #pragma unroll
    for (int mt = 0; mt < 2; ++mt)
      #pragma unroll
      for (int nt = 0; nt < 4; ++nt)
        #pragma unroll
        for (int q = 0; q < 4; ++q)
          part[pb][wv][mt * 16 + (lane >> 4) * 4 + q][nt * 16 + ln15] =
              acc_h[mt][nt][q] + INV2048 * acc_l[mt][nt][q];
    __syncthreads();  // the ONLY barrier
    float hkeep;
    {
      int u = tid & 7, n = tid >> 3;
      float s0 = bsum[0], s1 = bsum[1], s2 = bsum[2], s3 = bsum[3];
      #pragma unroll
      for (int w = 0; w < 8; ++w) {
        s0 += part[pb][w][u][n];
        s1 += part[pb][w][8 + u][n];
        s2 += part[pb][w][16 + u][n];
        s3 += part[pb][w][24 + u][n];
      }
      float is = sigm(s0), fs = sigm(s1), gt = tanh_f(s2), os = sigm(s3);
      c = fs * c + is * gt;
      hkeep = os * tanh_f(c);
      half_t hhi = (half_t)hkeep;
      half_t* hb = (layer == 0 ? h1h : h2h) + (long)(t & (NSLOT - 1)) * SLOTE;
      __hip_atomic_store((unsigned short*)&hb[n * 1024 + wg * 8 + u],
                         __builtin_bit_cast(unsigned short, hhi),
                         __ATOMIC_RELAXED, __HIP_MEMORY_SCOPE_AGENT);
    }
    // wave-level completion: drain own stores; 8th wave flags the WG
    asm volatile("s_waitcnt vmcnt(0)" ::: "memory");
    if (lane == 0) {
      int old = atomicAdd(&dcnt, 1);
      if (old == t * 8 + 7)
        __hip_atomic_store(fc + (layer * 128 + wg) * FSTRIDE, t + 1,
                           __ATOMIC_RELAXED, __HIP_MEMORY_SCOPE_AGENT);
    }
    // off-chain work AFTER the flag:
    if (layer == 1) {
      int u = tid & 7, n = tid >> 3;
      __builtin_nontemporal_store(hkeep, &out[((long)t * 64 + n) * 1024 + wg * 8 + u]);
    } else if (t + 1 < NSTEP) {
      // L2-prefetch next step's emb rows (same lines the t+1 gather will read)
      float dummy = 0.f;
      #pragma unroll
      for (int nt = 0; nt < 4; ++nt) {
        int tk2 = tokens[(t + 1) * 64 + nt * 16 + ln15];
        const float* r = emb + (long)tk2 * 1024 + wv * 128;
        #pragma unroll
        for (int j = 0; j < 4; ++j) dummy += r[j * 32];
      }
      asm volatile("" :: "v"(dummy));
    }
    if ((t & 31) == 31)  // periodic L2 invalidate: bounds h-ring staleness (32 < 64)
      __builtin_amdgcn_fence(__ATOMIC_ACQUIRE, "agent");
  }
}

extern "C" void kernel_launch(void* const* d_in, const int* in_sizes, int n_in,
                              void* d_out, int out_size, void* d_ws, size_t ws_size,
                              hipStream_t stream) {
  const int*   tokens = (const int*)d_in[0];
  const float* emb    = (const float*)d_in[1];
  const float* Wih    = (const float*)d_in[2];
  const float* Whh    = (const float*)d_in[3];
  const float* bih    = (const float*)d_in[4];
  const float* bhh    = (const float*)d_in[5];
  float* out = (float*)d_out;

  half_t* whi = (half_t*)d_ws;                            // 32 MB
  uchar*  wlo = (uchar*)((char*)d_ws + 33554432);         // 16 MB
  half_t* h1h = (half_t*)((char*)d_ws + 50331648);        // 8 MB (64 slots f16)
  half_t* h2h = (half_t*)((char*)d_ws + 58720256);        // 8 MB
  int* fc     = (int*)((char*)d_ws + 67108864);           // 64 KB strided counters

  hipLaunchKernelGGL(conv_w, dim3(65536), dim3(256), 0, stream, Wih, Whh, whi, wlo);
  hipMemsetAsync(fc, 0, 65536, stream);

  void* args[] = {(void*)&tokens, (void*)&emb, (void*)&bih, (void*)&bhh,
                  (void*)&whi, (void*)&wlo, (void*)&h1h, (void*)&h2h,
                  (void*)&fc, (void*)&out};
  hipError_t e = hipLaunchCooperativeKernel((const void*)lstm_main, dim3(256), dim3(512),
                                            args, 0, stream);
  if (e != hipSuccess) {
    hipMemsetAsync(d_out, 0x43, (size_t)out_size * 4, stream);
  }
}

// Round 23
// 7133.195 us; speedup vs baseline: 1.2359x; 1.2359x over previous
//
#include <hip/hip_runtime.h>

typedef _Float16 half_t;
typedef _Float16 half8 __attribute__((ext_vector_type(8)));
typedef float floatx4 __attribute__((ext_vector_type(4)));
typedef int int4v __attribute__((ext_vector_type(4)));
typedef unsigned uint4v __attribute__((ext_vector_type(4)));
typedef unsigned char uchar;

#define NSTEP 512
#define INV2048 (1.0f / 2048.0f)
#define NSLOT 64
#define SLOTE 65536  // 64 batch x 1024 units per ring slot (f16)
#define FSTRIDE 64   // flag counters 256B apart (one line each)

// ---- e5m2 codec: encode = f16 top byte (w/ rounding); decode = byte<<8 ----
__device__ __forceinline__ uchar enc_e5m2(float x) {
  half_t h = (half_t)x;
  unsigned b = (unsigned)__builtin_bit_cast(unsigned short, h);
  return (uchar)(((b + 0x80u) >> 8) & 0xffu);
}

__device__ __forceinline__ half8 dec8(unsigned w0, unsigned w1) {
  uint4v u;
  u[0] = ((w0 & 0x000000ffu) << 8) | ((w0 & 0x0000ff00u) << 16);
  u[1] = ((w0 & 0x00ff0000u) >> 8) | (w0 & 0xff000000u);
  u[2] = ((w1 & 0x000000ffu) << 8) | ((w1 & 0x0000ff00u) << 16);
  u[3] = ((w1 & 0x00ff0000u) >> 8) | (w1 & 0xff000000u);
  return __builtin_bit_cast(half8, u);
}

// hi blob: [layer(2)][wg(128)][wv(8)][frag(16)][lane(64)][i(8)] f16 (32 MB)
// lo blob: same index space, e5m2 of (v-hi)*2048 (16 MB)
// frag = prt*8 + kk*2 + mt (prt: 0=x-K-space, 1=h-K-space).
// A-row mloc = mt*16+(lane&15) -> gate=mloc>>3, u=mloc&7; grow = gate*1024+wg*8+u.
// k = prt*1024 + wv*128 + kk*32 + (lane>>4)*8 + i;  k<1024 Wih else Whh.
__global__ void conv_w(const float* __restrict__ Wih, const float* __restrict__ Whh,
                       half_t* __restrict__ whi, uchar* __restrict__ wlo) {
  long e = (long)blockIdx.x * 256 + threadIdx.x;  // 2^24
  int i    = (int)(e & 7);
  int lane = (int)((e >> 3) & 63);
  int frag = (int)((e >> 9) & 15);
  int wv   = (int)((e >> 13) & 7);
  int wg   = (int)((e >> 16) & 127);
  int layer = (int)((e >> 23) & 1);
  int mt = frag & 1, kk = (frag >> 1) & 3, prt = frag >> 3;
  int mloc = mt * 16 + (lane & 15);
  int grow = (mloc >> 3) * 1024 + wg * 8 + (mloc & 7);
  int k = prt * 1024 + wv * 128 + kk * 32 + ((lane >> 4) * 8) + i;
  long base = ((long)layer << 22) + (long)grow * 1024;
  float v = (k < 1024) ? Wih[base + k] : Whh[base + (k - 1024)];
  half_t hi = (half_t)v;
  whi[e] = hi;
  wlo[e] = enc_e5m2((v - (float)hi) * 2048.0f);
}

__device__ __forceinline__ float sigm(float x) { return 1.f / (1.f + __expf(-x)); }
__device__ __forceinline__ float tanh_f(float x) {
  x = fminf(15.f, fmaxf(-15.f, x));
  float e = __expf(-2.f * x);
  return (1.f - e) / (1.f + e);
}

// narrow poll: wave waits until 16 consecutive per-WG counters (strided) >= n
__device__ __forceinline__ void pollN(const int* fbase, int first, int n, int lane) {
  const int* p = fbase + (first + (lane & 15)) * FSTRIDE;
  while (__hip_atomic_load(p, __ATOMIC_RELAXED, __HIP_MEMORY_SCOPE_AGENT) < n)
    __builtin_amdgcn_s_sleep(2);
}

// full poll: all 128 counters >= n (amortized ring guard)
__device__ __forceinline__ void pollFull(const int* fbase, int n, int lane) {
  const int* p0 = fbase + lane * FSTRIDE;
  const int* p1 = fbase + (64 + lane) * FSTRIDE;
  for (;;) {
    int v0 = __hip_atomic_load(p0, __ATOMIC_RELAXED, __HIP_MEMORY_SCOPE_AGENT);
    int v1 = __hip_atomic_load(p1, __ATOMIC_RELAXED, __HIP_MEMORY_SCOPE_AGENT);
    if (__all((v0 >= n) && (v1 >= n))) break;
    __builtin_amdgcn_s_sleep(2);
  }
}

// 256 WGs x 512 thr. WGs [0,128): layer 0; [128,256): layer 1. Decoupled layers.
// R21 structure (best: narrow single-hop flags, fused L1 poll, one barrier/step,
// double-buffered part, weights fully in VGPRs) with one tweak: L0 computes its
// x-part BEFORE its recurrence poll (pure reorder -> poll often returns free).
__launch_bounds__(512, 1)
__global__ void lstm_main(const int* __restrict__ tokens, const float* __restrict__ emb,
                          const float* __restrict__ bih, const float* __restrict__ bhh,
                          const half_t* __restrict__ whi, const uchar* __restrict__ wlo,
                          half_t* __restrict__ h1h, half_t* __restrict__ h2h,
                          int* __restrict__ fc, float* __restrict__ out) {
  __shared__ float part[2][8][32][68];   // 139 KB, double-buffered per-wave slices
  __shared__ int dcnt;                   // monotonic completion counter
  const int wgid = blockIdx.x;
  const int layer = wgid >> 7;
  const int wg = wgid & 127;
  const int tid = (int)threadIdx.x;
  const int wv = tid >> 6;
  const int lane = tid & 63;
  const int ln15 = lane & 15;
  const int kr = (lane >> 4) * 8;

  const int* f0 = fc;                  // layer-0 counters, FSTRIDE apart
  const int* f1 = fc + 128 * FSTRIDE;  // layer-1 counters

  // hi-weights -> 64 persistent VGPRs (frag 0..7 = x, 8..15 = h)
  half8 whi_r[16];
  {
    const half_t* wb = whi + (((long)(layer * 128 + wg)) << 16) + wv * 8192;
    #pragma unroll
    for (int f = 0; f < 16; ++f)
      whi_r[f] = *(const half8*)(wb + f * 512 + lane * 8);
  }
  // e5m2 lo-weights -> 32 persistent VGPRs
  unsigned lw[16][2];
  {
    const uchar* lobw = wlo + (((long)(layer * 128 + wg)) << 16) + wv * 8192;
    #pragma unroll
    for (int f = 0; f < 16; ++f) {
      const unsigned* l = (const unsigned*)(lobw + (f << 9) + lane * 8);
      lw[f][0] = l[0]; lw[f][1] = l[1];
    }
  }

  float bsum[4];
  {
    int u = tid & 7;
    for (int g = 0; g < 4; ++g) {
      int bi = layer * 4096 + g * 1024 + wg * 8 + u;
      bsum[g] = bih[bi] + bhh[bi];
    }
  }
  float c = 0.f;
  if (tid == 0) dcnt = 0;
  __syncthreads();

  for (int t = 0; t < NSTEP; ++t) {
    floatx4 zero = {0.f, 0.f, 0.f, 0.f};
    floatx4 acc_h[2][4], acc_l[2][4];
    for (int a = 0; a < 2; ++a)
      for (int b = 0; b < 4; ++b) { acc_h[a][b] = zero; acc_l[a][b] = zero; }

    if (layer == 0) {
      // ring-overwrite guard (amortized, margin 32)
      if ((t & 15) == 0 && t >= 33) pollFull(f1, t - 32, lane);

      // ---- x-part FIRST (no flag dependency) ----
      int tk[4]; const float* rowp[4]; float msk[4];
      #pragma unroll
      for (int nt = 0; nt < 4; ++nt) {
        tk[nt] = tokens[t * 64 + nt * 16 + ln15];
        rowp[nt] = emb + (long)tk[nt] * 1024;
        msk[nt] = (tk[nt] == 0) ? 0.f : 1.f;
      }
      floatx4 bx0[2][4], bx1[2][4];
      {
        int kb = wv * 128 + kr;
        #pragma unroll
        for (int nt = 0; nt < 4; ++nt) {
          bx0[0][nt] = *(const floatx4*)(rowp[nt] + kb);
          bx1[0][nt] = *(const floatx4*)(rowp[nt] + kb + 4);
        }
      }
      #pragma unroll
      for (int kk = 0; kk < 4; ++kk) {
        const int cb = kk & 1, nx = cb ^ 1;
        if (kk < 3) {
          int kb = wv * 128 + (kk + 1) * 32 + kr;
          #pragma unroll
          for (int nt = 0; nt < 4; ++nt) {
            bx0[nx][nt] = *(const floatx4*)(rowp[nt] + kb);
            bx1[nx][nt] = *(const floatx4*)(rowp[nt] + kb + 4);
          }
        }
        half8 ah0 = whi_r[kk * 2];
        half8 ah1 = whi_r[kk * 2 + 1];
        half8 al0 = dec8(lw[kk * 2][0], lw[kk * 2][1]);
        half8 al1 = dec8(lw[kk * 2 + 1][0], lw[kk * 2 + 1][1]);
        #pragma unroll
        for (int nt = 0; nt < 4; ++nt) {
          half8 bh;
          #pragma unroll
          for (int q = 0; q < 4; ++q) {
            bh[q]     = (half_t)(bx0[cb][nt][q] * msk[nt]);
            bh[q + 4] = (half_t)(bx1[cb][nt][q] * msk[nt]);
          }
          acc_h[0][nt] = __builtin_amdgcn_mfma_f32_16x16x32_f16(ah0, bh, acc_h[0][nt], 0, 0, 0);
          acc_h[1][nt] = __builtin_amdgcn_mfma_f32_16x16x32_f16(ah1, bh, acc_h[1][nt], 0, 0, 0);
          acc_l[0][nt] = __builtin_amdgcn_mfma_f32_16x16x32_f16(al0, bh, acc_l[0][nt], 0, 0, 0);
          acc_l[1][nt] = __builtin_amdgcn_mfma_f32_16x16x32_f16(al1, bh, acc_l[1][nt], 0, 0, 0);
        }
      }
      // ---- recurrence poll AFTER x (often already satisfied) ----
      if (t > 0) pollN(f0, wv * 16, t, lane);
    } else {
      // ---- L1: FUSED poll (lanes 0-15: f1 >= t ; lanes 16-31: f0 >= t+1) ----
      const int sel = (lane >> 4) & 1;
      const int* p = (sel ? f0 : f1) + (wv * 16 + ln15) * FSTRIDE;
      const int thr = sel ? (t + 1) : t;
      while (__hip_atomic_load(p, __ATOMIC_RELAXED, __HIP_MEMORY_SCOPE_AGENT) < thr)
        __builtin_amdgcn_s_sleep(2);

      const half_t* abh = h1h + (long)(t & (NSLOT - 1)) * SLOTE;
      const int kofs = wv * 128;
      half8 bufh[4][4];
      #pragma unroll
      for (int kk = 0; kk < 4; ++kk) {
        int kb = kofs + kk * 32 + kr;
        #pragma unroll
        for (int nt = 0; nt < 4; ++nt)
          bufh[kk][nt] = *(const half8*)(abh + (nt * 16 + ln15) * 1024 + kb);
      }
      #pragma unroll
      for (int kk = 0; kk < 4; ++kk) {
        half8 ah0 = whi_r[kk * 2];
        half8 ah1 = whi_r[kk * 2 + 1];
        half8 al0 = dec8(lw[kk * 2][0], lw[kk * 2][1]);
        half8 al1 = dec8(lw[kk * 2 + 1][0], lw[kk * 2 + 1][1]);
        #pragma unroll
        for (int nt = 0; nt < 4; ++nt) {
          half8 bh = bufh[kk][nt];
          acc_h[0][nt] = __builtin_amdgcn_mfma_f32_16x16x32_f16(ah0, bh, acc_h[0][nt], 0, 0, 0);
          acc_h[1][nt] = __builtin_amdgcn_mfma_f32_16x16x32_f16(ah1, bh, acc_h[1][nt], 0, 0, 0);
          acc_l[0][nt] = __builtin_amdgcn_mfma_f32_16x16x32_f16(al0, bh, acc_l[0][nt], 0, 0, 0);
          acc_l[1][nt] = __builtin_amdgcn_mfma_f32_16x16x32_f16(al1, bh, acc_l[1][nt], 0, 0, 0);
        }
      }
    }

    // ---- h-part: 128 k per wave (4 kk), frags 8..15 ----
    if (t > 0) {
      const half_t* abh = (layer == 0 ? h1h : h2h) + (long)((t - 1) & (NSLOT - 1)) * SLOTE;
      const int kofs = wv * 128;
      half8 bufh[4][4];
      #pragma unroll
      for (int kk = 0; kk < 4; ++kk) {
        int kb = kofs + kk * 32 + kr;
        #pragma unroll
        for (int nt = 0; nt < 4; ++nt)
          bufh[kk][nt] = *(const half8*)(abh + (nt * 16 + ln15) * 1024 + kb);
      }
      #pragma unroll
      for (int kk = 0; kk < 4; ++kk) {
        half8 ah0 = whi_r[8 + kk * 2];
        half8 ah1 = whi_r[8 + kk * 2 + 1];
        half8 al0 = dec8(lw[8 + kk * 2][0], lw[8 + kk * 2][1]);
        half8 al1 = dec8(lw[8 + kk * 2 + 1][0], lw[8 + kk * 2 + 1][1]);
        #pragma unroll
        for (int nt = 0; nt < 4; ++nt) {
          half8 bh = bufh[kk][nt];
          acc_h[0][nt] = __builtin_amdgcn_mfma_f32_16x16x32_f16(ah0, bh, acc_h[0][nt], 0, 0, 0);
          acc_h[1][nt] = __builtin_amdgcn_mfma_f32_16x16x32_f16(ah1, bh, acc_h[1][nt], 0, 0, 0);
          acc_l[0][nt] = __builtin_amdgcn_mfma_f32_16x16x32_f16(al0, bh, acc_l[0][nt], 0, 0, 0);
          acc_l[1][nt] = __builtin_amdgcn_mfma_f32_16x16x32_f16(al1, bh, acc_l[1][nt], 0, 0, 0);
        }
      }
    }

    // plain per-wave slice write into buffer t&1 (exact coverage)
    const int pb = t & 1;
    #pragma unroll
    for (int mt = 0; mt < 2; ++mt)
      #pragma unroll
      for (int nt = 0; nt < 4; ++nt)
        #pragma unroll
        for (int q = 0; q < 4; ++q)
          part[pb][wv][mt * 16 + (lane >> 4) * 4 + q][nt * 16 + ln15] =
              acc_h[mt][nt][q] + INV2048 * acc_l[mt][nt][q];
    __syncthreads();  // the ONLY barrier
    float hkeep;
    {
      int u = tid & 7, n = tid >> 3;
      float s0 = bsum[0], s1 = bsum[1], s2 = bsum[2], s3 = bsum[3];
      #pragma unroll
      for (int w = 0; w < 8; ++w) {
        s0 += part[pb][w][u][n];
        s1 += part[pb][w][8 + u][n];
        s2 += part[pb][w][16 + u][n];
        s3 += part[pb][w][24 + u][n];
      }
      float is = sigm(s0), fs = sigm(s1), gt = tanh_f(s2), os = sigm(s3);
      c = fs * c + is * gt;
      hkeep = os * tanh_f(c);
      half_t hhi = (half_t)hkeep;
      half_t* hb = (layer == 0 ? h1h : h2h) + (long)(t & (NSLOT - 1)) * SLOTE;
      __hip_atomic_store((unsigned short*)&hb[n * 1024 + wg * 8 + u],
                         __builtin_bit_cast(unsigned short, hhi),
                         __ATOMIC_RELAXED, __HIP_MEMORY_SCOPE_AGENT);
    }
    // wave-level completion: drain own stores; 8th wave flags the WG
    asm volatile("s_waitcnt vmcnt(0)" ::: "memory");
    if (lane == 0) {
      int old = atomicAdd(&dcnt, 1);
      if (old == t * 8 + 7)
        __hip_atomic_store(fc + (layer * 128 + wg) * FSTRIDE, t + 1,
                           __ATOMIC_RELAXED, __HIP_MEMORY_SCOPE_AGENT);
    }
    // out store AFTER the flag path: HBM drain leaves the critical chain
    if (layer == 1) {
      int u = tid & 7, n = tid >> 3;
      __builtin_nontemporal_store(hkeep, &out[((long)t * 64 + n) * 1024 + wg * 8 + u]);
    }
    if ((t & 31) == 31)  // periodic L2 invalidate: bounds h-ring staleness (32 < 64)
      __builtin_amdgcn_fence(__ATOMIC_ACQUIRE, "agent");
  }
}

extern "C" void kernel_launch(void* const* d_in, const int* in_sizes, int n_in,
                              void* d_out, int out_size, void* d_ws, size_t ws_size,
                              hipStream_t stream) {
  const int*   tokens = (const int*)d_in[0];
  const float* emb    = (const float*)d_in[1];
  const float* Wih    = (const float*)d_in[2];
  const float* Whh    = (const float*)d_in[3];
  const float* bih    = (const float*)d_in[4];
  const float* bhh    = (const float*)d_in[5];
  float* out = (float*)d_out;

  half_t* whi = (half_t*)d_ws;                            // 32 MB
  uchar*  wlo = (uchar*)((char*)d_ws + 33554432);         // 16 MB
  half_t* h1h = (half_t*)((char*)d_ws + 50331648);        // 8 MB (64 slots f16)
  half_t* h2h = (half_t*)((char*)d_ws + 58720256);        // 8 MB
  int* fc     = (int*)((char*)d_ws + 67108864);           // 64 KB strided counters

  hipLaunchKernelGGL(conv_w, dim3(65536), dim3(256), 0, stream, Wih, Whh, whi, wlo);
  hipMemsetAsync(fc, 0, 65536, stream);

  void* args[] = {(void*)&tokens, (void*)&emb, (void*)&bih, (void*)&bhh,
                  (void*)&whi, (void*)&wlo, (void*)&h1h, (void*)&h2h,
                  (void*)&fc, (void*)&out};
  hipError_t e = hipLaunchCooperativeKernel((const void*)lstm_main, dim3(256), dim3(512),
                                            args, 0, stream);
  if (e != hipSuccess) {
    hipMemsetAsync(d_out, 0x43, (size_t)out_size * 4, stream);
  }
}